// Round 5
// baseline (369.015 us; speedup 1.0000x reference)
//
#include <hip/hip_runtime.h>
#include <math.h>

#define N_EXP 64
#define TOPK 8
#define TOPK_G 4
#define D_DIM 2048
#define BM 128
#define WAVES 8
#define THREADS 512
#define KHALF 1024
#define KW (KHALF / WAVES)   // 128 k per wave
#define BK 8
#define NCHUNK (KW / BK)     // 16
#define S_TOT 16384

// kernel 1: GEMM partials. grid 256 = 128 row-blocks x 2 k-halves, 512 thr.
// Per-thread 16x8 tile (rows split in two planes at +64). LDS 96 KB:
// wave w at [w*3072]: x dbuf [2][8k][128r] (2048), W dbuf [2][8k][64e] (1024).
// Reduction overlays part[2][128][64] at [0].
__launch_bounds__(THREADS)
__global__ void gemm_half_kernel(const float* __restrict__ x,
                                 const float* __restrict__ W,
                                 float* __restrict__ part)
{
    __shared__ float smem[24576];

    const int tid  = threadIdx.x;
    const int wave = tid >> 6;
    const int lane = tid & 63;
    const int lm   = lane >> 3;   // row-group: rows lm*8+i (plane A), +64 (plane B)
    const int ln   = lane & 7;    // expert-group: exps ln*8+j
    const int rb   = blockIdx.x >> 1;
    const int kh   = blockIdx.x & 1;
    const int row0 = rb * BM;
    const int xb   = wave * 3072;
    const int wb   = xb + 2048;

    const float* xr0 = x + (size_t)(row0 + lane) * D_DIM + kh * KHALF + wave * KW;
    const float* xr1 = xr0 + (size_t)64 * D_DIM;
    const float* wr  = W + (size_t)lane * D_DIM + kh * KHALF + wave * KW;

    float accA[8][8], accB[8][8];
#pragma unroll
    for (int i = 0; i < 8; ++i)
#pragma unroll
        for (int j = 0; j < 8; ++j) { accA[i][j] = 0.f; accB[i][j] = 0.f; }

    float4 gx0, gx1, gx2, gx3, gw0, gw1;

#define LOADG(c) do { \
        gx0 = *(const float4*)(xr0 + (c) * BK);     gx1 = *(const float4*)(xr0 + (c) * BK + 4); \
        gx2 = *(const float4*)(xr1 + (c) * BK);     gx3 = *(const float4*)(xr1 + (c) * BK + 4); \
        gw0 = *(const float4*)(wr  + (c) * BK);     gw1 = *(const float4*)(wr  + (c) * BK + 4); \
    } while (0)

#define STOREG(p) do { \
        const int o = xb + (p) * 1024; \
        smem[o + 0*128 + lane] = gx0.x; smem[o + 1*128 + lane] = gx0.y; \
        smem[o + 2*128 + lane] = gx0.z; smem[o + 3*128 + lane] = gx0.w; \
        smem[o + 4*128 + lane] = gx1.x; smem[o + 5*128 + lane] = gx1.y; \
        smem[o + 6*128 + lane] = gx1.z; smem[o + 7*128 + lane] = gx1.w; \
        smem[o + 0*128 + 64 + lane] = gx2.x; smem[o + 1*128 + 64 + lane] = gx2.y; \
        smem[o + 2*128 + 64 + lane] = gx2.z; smem[o + 3*128 + 64 + lane] = gx2.w; \
        smem[o + 4*128 + 64 + lane] = gx3.x; smem[o + 5*128 + 64 + lane] = gx3.y; \
        smem[o + 6*128 + 64 + lane] = gx3.z; smem[o + 7*128 + 64 + lane] = gx3.w; \
        const int ow = wb + (p) * 512; \
        smem[ow + 0*64 + lane] = gw0.x; smem[ow + 1*64 + lane] = gw0.y; \
        smem[ow + 2*64 + lane] = gw0.z; smem[ow + 3*64 + lane] = gw0.w; \
        smem[ow + 4*64 + lane] = gw1.x; smem[ow + 5*64 + lane] = gw1.y; \
        smem[ow + 6*64 + lane] = gw1.z; smem[ow + 7*64 + lane] = gw1.w; \
    } while (0)

    LOADG(0);
    STOREG(0);
    LOADG(1);

    for (int c = 0; c < NCHUNK; ++c) {
        if (c + 1 < NCHUNK) STOREG((c + 1) & 1);
        if (c + 2 < NCHUNK) LOADG(c + 2);
        const int cb = xb + (c & 1) * 1024;
        const int cw = wb + (c & 1) * 512;
#pragma unroll
        for (int k = 0; k < BK; ++k) {
            float fa[8], fb[8], fwv[8];
            *(float4*)&fa[0]  = *(const float4*)&smem[cb + k * 128 + lm * 8];
            *(float4*)&fa[4]  = *(const float4*)&smem[cb + k * 128 + lm * 8 + 4];
            *(float4*)&fb[0]  = *(const float4*)&smem[cb + k * 128 + 64 + lm * 8];
            *(float4*)&fb[4]  = *(const float4*)&smem[cb + k * 128 + 64 + lm * 8 + 4];
            *(float4*)&fwv[0] = *(const float4*)&smem[cw + k * 64 + ln * 8];
            *(float4*)&fwv[4] = *(const float4*)&smem[cw + k * 64 + ln * 8 + 4];
#pragma unroll
            for (int i = 0; i < 8; ++i)
#pragma unroll
                for (int j = 0; j < 8; ++j) {
                    accA[i][j] = fmaf(fa[i], fwv[j], accA[i][j]);
                    accB[i][j] = fmaf(fb[i], fwv[j], accB[i][j]);
                }
        }
    }
#undef LOADG
#undef STOREG

    // cross-wave k-reduction: 4 rounds x 2 writer waves into part[2][128][64]
    float red[16];
#pragma unroll
    for (int j = 0; j < 16; ++j) red[j] = 0.f;
    const int r2  = tid >> 2;         // 0..127
    const int eq  = (tid & 3) * 16;
    const int rsw = 4 * (r2 >> 3);

    for (int rj = 0; rj < 4; ++rj) {
        __syncthreads(); // rj=0: GEMM LDS done; else prior round reads done
        if ((wave >> 1) == rj) {
            const int p = wave & 1;
#pragma unroll
            for (int i = 0; i < 8; ++i) {
#pragma unroll
                for (int q = 0; q < 2; ++q) {
                    const int ecA = (ln * 8 + q * 4 + 4 * lm) & 63;
                    const int ecB = (ecA + 32) & 63;
                    *(float4*)&smem[p * 8192 + (lm * 8 + i) * 64 + ecA] =
                        make_float4(accA[i][q*4+0], accA[i][q*4+1], accA[i][q*4+2], accA[i][q*4+3]);
                    *(float4*)&smem[p * 8192 + (64 + lm * 8 + i) * 64 + ecB] =
                        make_float4(accB[i][q*4+0], accB[i][q*4+1], accB[i][q*4+2], accB[i][q*4+3]);
                }
            }
        }
        __syncthreads();
#pragma unroll
        for (int p = 0; p < 2; ++p) {
#pragma unroll
            for (int q = 0; q < 4; ++q) {
                const int ec = (eq + q * 4 + rsw) & 63;
                const float4 v = *(const float4*)&smem[p * 8192 + r2 * 64 + ec];
                red[q*4+0] += v.x; red[q*4+1] += v.y; red[q*4+2] += v.z; red[q*4+3] += v.w;
            }
        }
    }

    // store partial logits, coalesced
    float* dst = part + ((size_t)kh * S_TOT + row0 + r2) * N_EXP + eq;
    *(float4*)(dst)      = make_float4(red[0],  red[1],  red[2],  red[3]);
    *(float4*)(dst + 4)  = make_float4(red[4],  red[5],  red[6],  red[7]);
    *(float4*)(dst + 8)  = make_float4(red[8],  red[9],  red[10], red[11]);
    *(float4*)(dst + 12) = make_float4(red[12], red[13], red[14], red[15]);
}

// kernel 2: sum halves + sigmoid + grouped top-k. 256 thr (4 waves), 64 rows/block.
__global__ void select_kernel(const float* __restrict__ part,
                              const float* __restrict__ bias,
                              float* __restrict__ out_idx,
                              float* __restrict__ out_w)
{
    __shared__ float sc[64 * 65];
    __shared__ float bias_s[64];

    const int tid = threadIdx.x;          // 256 threads
    const int r   = tid >> 2;             // row within block 0..63
    const int seg = (tid & 3) * 16;       // 16 experts per thread
    const int row = blockIdx.x * 64 + r;

    const float* p0 = part + (size_t)row * N_EXP + seg;
    const float* p1 = p0 + (size_t)S_TOT * N_EXP;
#pragma unroll
    for (int q = 0; q < 4; ++q) {
        float4 a = *(const float4*)(p0 + q * 4);
        float4 b = *(const float4*)(p1 + q * 4);
        sc[r * 65 + seg + q * 4 + 0] = 1.0f / (1.0f + expf(-(a.x + b.x)));
        sc[r * 65 + seg + q * 4 + 1] = 1.0f / (1.0f + expf(-(a.y + b.y)));
        sc[r * 65 + seg + q * 4 + 2] = 1.0f / (1.0f + expf(-(a.z + b.z)));
        sc[r * 65 + seg + q * 4 + 3] = 1.0f / (1.0f + expf(-(a.w + b.w)));
    }
    if (tid < 64) bias_s[tid] = bias[tid];
    __syncthreads();

    if (tid < 64) {
        const int rr = tid;
        float gmax[8];
#pragma unroll
        for (int g = 0; g < 8; ++g) {
            float m = -INFINITY;
#pragma unroll
            for (int j = 0; j < 8; ++j) {
                float v = sc[rr * 65 + g * 8 + j] + bias_s[g * 8 + j];
                m = fmaxf(m, v);
            }
            gmax[g] = m;
        }
        unsigned gsel = 0;
        for (int k = 0; k < TOPK_G; ++k) {
            int best = 0; float bv = -INFINITY;
#pragma unroll
            for (int g = 0; g < 8; ++g)
                if (!((gsel >> g) & 1) && gmax[g] > bv) { bv = gmax[g]; best = g; }
            gsel |= 1u << best;
        }
        unsigned long long emask = 0ull;
#pragma unroll
        for (int g = 0; g < 8; ++g)
            if ((gsel >> g) & 1) emask |= (0xFFull << (g * 8));

        const int grow = blockIdx.x * 64 + rr;
        unsigned long long esel = 0ull;
        float wsum = 0.f;
        float wv[TOPK]; int iv[TOPK];
        for (int k = 0; k < TOPK; ++k) {
            int best = 0; float bv = -INFINITY;
            for (int e = 0; e < N_EXP; ++e) {
                if (((emask >> e) & 1) && !((esel >> e) & 1)) {
                    float v = sc[rr * 65 + e] + bias_s[e];
                    if (v > bv) { bv = v; best = e; }
                }
            }
            esel |= 1ull << best;
            iv[k] = best;
            wv[k] = sc[rr * 65 + best];
            wsum += wv[k];
        }
        const float inv = 1.0f / (wsum + 1e-20f);
#pragma unroll
        for (int k = 0; k < TOPK; ++k) {
            out_idx[grow * TOPK + k] = (float)iv[k];
            out_w[grow * TOPK + k]   = wv[k] * inv;
        }
    }
}

extern "C" void kernel_launch(void* const* d_in, const int* in_sizes, int n_in,
                              void* d_out, int out_size, void* d_ws, size_t ws_size,
                              hipStream_t stream) {
    const float* x    = (const float*)d_in[0];
    const float* W    = (const float*)d_in[1];
    const float* bias = (const float*)d_in[2];
    float* out  = (float*)d_out;
    float* part = (float*)d_ws; // 2*16384*64*4 = 8 MB scratch

    hipLaunchKernelGGL(gemm_half_kernel, dim3((S_TOT / BM) * 2), dim3(THREADS), 0, stream,
                       x, W, part);
    hipLaunchKernelGGL(select_kernel, dim3(S_TOT / 64), dim3(256), 0, stream,
                       part, bias, out, out + S_TOT * TOPK);
}